// Round 1
// baseline (245.351 us; speedup 1.0000x reference)
//
#include <hip/hip_runtime.h>
#include <cstdint>
#include <cstddef>

// ---------- constants for this problem ----------
#define BATCH 2
#define SEQ   2048
#define HID   1024
#define NHEAD 16
#define DHEAD 64
#define QKV_N 3072   // 3*HID
#define NTOK  4096   // BATCH*SEQ

typedef __attribute__((ext_vector_type(4))) float f32x4;
typedef __attribute__((ext_vector_type(8))) short bf16x8;

__device__ inline unsigned short f2bf(float f) {
    union { float f; unsigned int u; } v; v.f = f;
    unsigned int u = v.u;
    unsigned int r = (u + 0x7fffu + ((u >> 16) & 1u)) >> 16;
    return (unsigned short)r;
}

// ---------- cast fp32 -> bf16 (packed ushort4) ----------
__global__ void cast_f32_bf16(const float* __restrict__ in, unsigned short* __restrict__ out, int n4) {
    int i = blockIdx.x * blockDim.x + threadIdx.x;
    if (i >= n4) return;
    float4 v = reinterpret_cast<const float4*>(in)[i];
    ushort4 o;
    o.x = f2bf(v.x); o.y = f2bf(v.y); o.z = f2bf(v.z); o.w = f2bf(v.w);
    reinterpret_cast<ushort4*>(out)[i] = o;
}

// ---------- GEMM: C[M][N] = A[M][K](bf16) @ B[N][K](bf16)^T + bias (fp32) ----------
// tile 128x128, BK=32, 4 waves (2x2), each wave 64x64 via 4x4 frags of 16x16x32
#define LDP 40   // LDS row pitch in bf16 elements (32 + 8 pad)

template<bool OUT_BF16>
__global__ __launch_bounds__(256) void gemm_bt(const short* __restrict__ A,
                                               const short* __restrict__ B,
                                               const float* __restrict__ bias,
                                               void* __restrict__ Cout,
                                               int M, int N, int K) {
    __shared__ short sA[128 * LDP];
    __shared__ short sB[128 * LDP];
    const int tid  = threadIdx.x;
    const int lane = tid & 63;
    const int wave = tid >> 6;
    const int wm = wave >> 1, wn = wave & 1;
    const int m0 = blockIdx.y * 128;
    const int n0 = blockIdx.x * 128;

    f32x4 acc[4][4];
    #pragma unroll
    for (int i = 0; i < 4; ++i)
        #pragma unroll
        for (int j = 0; j < 4; ++j) acc[i][j] = (f32x4){0.f, 0.f, 0.f, 0.f};

    const int srow = tid >> 1;          // 0..127
    const int soff = (tid & 1) * 2;     // int4-chunk offset {0,2} within row
    const int r  = lane & 15;
    const int ko = (lane >> 4) * 8;

    for (int kt = 0; kt < K; kt += 32) {
        __syncthreads();
        {
            const int4* ga = reinterpret_cast<const int4*>(A + (size_t)(m0 + srow) * K + kt + soff * 8);
            int4 a0 = ga[0]; int4 a1 = ga[1];
            const int4* gb = reinterpret_cast<const int4*>(B + (size_t)(n0 + srow) * K + kt + soff * 8);
            int4 b0 = gb[0]; int4 b1 = gb[1];
            *reinterpret_cast<int4*>(&sA[srow * LDP + soff * 8])     = a0;
            *reinterpret_cast<int4*>(&sA[srow * LDP + soff * 8 + 8]) = a1;
            *reinterpret_cast<int4*>(&sB[srow * LDP + soff * 8])     = b0;
            *reinterpret_cast<int4*>(&sB[srow * LDP + soff * 8 + 8]) = b1;
        }
        __syncthreads();

        bf16x8 af[4], bfr[4];
        #pragma unroll
        for (int i = 0; i < 4; ++i) {
            af[i]  = *reinterpret_cast<const bf16x8*>(&sA[(wm * 64 + i * 16 + r) * LDP + ko]);
            bfr[i] = *reinterpret_cast<const bf16x8*>(&sB[(wn * 64 + i * 16 + r) * LDP + ko]);
        }
        #pragma unroll
        for (int i = 0; i < 4; ++i)
            #pragma unroll
            for (int j = 0; j < 4; ++j)
                acc[i][j] = __builtin_amdgcn_mfma_f32_16x16x32_bf16(af[i], bfr[j], acc[i][j], 0, 0, 0);
    }

    // epilogue: D layout col=lane&15, row=4*(lane>>4)+reg
    const int col_l = lane & 15;
    const int row_g = (lane >> 4) * 4;
    #pragma unroll
    for (int i = 0; i < 4; ++i) {
        #pragma unroll
        for (int j = 0; j < 4; ++j) {
            int nn = n0 + wn * 64 + j * 16 + col_l;
            float bv = bias[nn];
            #pragma unroll
            for (int reg = 0; reg < 4; ++reg) {
                int mm = m0 + wm * 64 + i * 16 + row_g + reg;
                float v = acc[i][j][reg] + bv;
                if (OUT_BF16) {
                    reinterpret_cast<unsigned short*>(Cout)[(size_t)mm * N + nn] = f2bf(v);
                } else {
                    reinterpret_cast<float*>(Cout)[(size_t)mm * N + nn] = v;
                }
            }
        }
    }
}

// ---------- flash attention (causal), bf16 MFMA ----------
// grid: x = SEQ/64 q-blocks, y = BATCH*NHEAD. 256 threads = 4 waves, each wave 16 q-rows.
#define KLDP 72  // LDS pitch for K / V^T / P tiles (64 + 8 pad)

__global__ __launch_bounds__(256) void attn_fwd(const short* __restrict__ qkv,
                                                short* __restrict__ av) {
    const int bh = blockIdx.y;
    const int b  = bh >> 4;        // NHEAD = 16
    const int h  = bh & 15;
    const int qb = blockIdx.x;

    __shared__ short sK[64 * KLDP];        // K tile [kv][d]
    __shared__ short sV[64 * KLDP];        // V^T tile [d][kv]
    __shared__ short sP[4][16 * KLDP];     // per-wave P tile [row][kv]

    const int tid  = threadIdx.x;
    const int lane = tid & 63;
    const int wave = tid >> 6;
    const int q_base = qb * 64 + wave * 16;

    const int r  = lane & 15;
    const int ko = (lane >> 4) * 8;
    const int row_g = (lane >> 4) * 4;

    // load Q fragments (held in registers for the whole kv loop)
    const short* Qg = qkv + ((size_t)(b * SEQ + q_base + r)) * QKV_N + h * DHEAD;
    bf16x8 qf0 = *reinterpret_cast<const bf16x8*>(Qg + ko);
    bf16x8 qf1 = *reinterpret_cast<const bf16x8*>(Qg + 32 + ko);

    f32x4 oacc[4];
    #pragma unroll
    for (int i = 0; i < 4; ++i) oacc[i] = (f32x4){0.f, 0.f, 0.f, 0.f};
    float mr[4], lr[4];
    #pragma unroll
    for (int i = 0; i < 4; ++i) { mr[i] = -3.0e38f; lr[i] = 0.f; }

    for (int t = 0; t <= qb; ++t) {
        const int kv0 = t * 64;
        __syncthreads();
        // stage K tile: 8KB, 2 x int4 per thread
        {
            const int krow = tid >> 2;            // 0..63
            const int koff = (tid & 3) * 2;       // int4 chunk {0,2,4,6}
            const int4* gk = reinterpret_cast<const int4*>(
                qkv + ((size_t)(b * SEQ + kv0 + krow)) * QKV_N + HID + h * DHEAD + koff * 8);
            int4 k0 = gk[0]; int4 k1 = gk[1];
            *reinterpret_cast<int4*>(&sK[krow * KLDP + koff * 8])     = k0;
            *reinterpret_cast<int4*>(&sK[krow * KLDP + koff * 8 + 8]) = k1;
        }
        // stage V transposed: scalar (coalesced-ish reads)
        #pragma unroll
        for (int i = 0; i < 16; ++i) {
            int e  = i * 256 + tid;
            int kv = e >> 6, d = e & 63;
            short vv = qkv[((size_t)(b * SEQ + kv0 + kv)) * QKV_N + 2 * HID + h * DHEAD + d];
            sV[d * KLDP + kv] = vv;
        }
        __syncthreads();

        // S = (Q @ K^T) * 1/8  -- 4 kv-groups of 16
        f32x4 s[4];
        #pragma unroll
        for (int g = 0; g < 4; ++g) {
            f32x4 z = (f32x4){0.f, 0.f, 0.f, 0.f};
            bf16x8 kb0 = *reinterpret_cast<const bf16x8*>(&sK[(g * 16 + r) * KLDP + ko]);
            bf16x8 kb1 = *reinterpret_cast<const bf16x8*>(&sK[(g * 16 + r) * KLDP + 32 + ko]);
            z = __builtin_amdgcn_mfma_f32_16x16x32_bf16(qf0, kb0, z, 0, 0, 0);
            z = __builtin_amdgcn_mfma_f32_16x16x32_bf16(qf1, kb1, z, 0, 0, 0);
            s[g] = z;
        }
        const bool diag = (t == qb);
        #pragma unroll
        for (int g = 0; g < 4; ++g) {
            #pragma unroll
            for (int reg = 0; reg < 4; ++reg) {
                float sv = s[g][reg] * 0.125f;
                if (diag) {
                    int kvg = kv0 + g * 16 + r;          // D col = lane&15
                    int qg  = q_base + row_g + reg;      // D row
                    if (kvg > qg) sv = -1.0e30f;
                }
                s[g][reg] = sv;
            }
        }

        // row max over 64 kv (4 groups x 16 lanes)
        float rm[4];
        #pragma unroll
        for (int reg = 0; reg < 4; ++reg) {
            float v = s[0][reg];
            v = fmaxf(v, s[1][reg]); v = fmaxf(v, s[2][reg]); v = fmaxf(v, s[3][reg]);
            rm[reg] = v;
        }
        #pragma unroll
        for (int m = 1; m <= 8; m <<= 1) {
            #pragma unroll
            for (int reg = 0; reg < 4; ++reg)
                rm[reg] = fmaxf(rm[reg], __shfl_xor(rm[reg], m));
        }

        float mnew[4], corr[4];
        #pragma unroll
        for (int reg = 0; reg < 4; ++reg) {
            mnew[reg] = fmaxf(mr[reg], rm[reg]);
            corr[reg] = __expf(mr[reg] - mnew[reg]);
            lr[reg]  *= corr[reg];
            mr[reg]   = mnew[reg];
        }
        #pragma unroll
        for (int dg = 0; dg < 4; ++dg)
            #pragma unroll
            for (int reg = 0; reg < 4; ++reg)
                oacc[dg][reg] *= corr[reg];

        // P = exp(S - m), accumulate row sums
        float ps[4] = {0.f, 0.f, 0.f, 0.f};
        #pragma unroll
        for (int g = 0; g < 4; ++g) {
            #pragma unroll
            for (int reg = 0; reg < 4; ++reg) {
                float p = __expf(s[g][reg] - mnew[reg]);
                s[g][reg] = p;
                ps[reg] += p;
            }
        }
        #pragma unroll
        for (int m = 1; m <= 8; m <<= 1) {
            #pragma unroll
            for (int reg = 0; reg < 4; ++reg)
                ps[reg] += __shfl_xor(ps[reg], m);
        }
        #pragma unroll
        for (int reg = 0; reg < 4; ++reg) lr[reg] += ps[reg];

        // write P (bf16) to per-wave LDS in [row][kv] layout
        #pragma unroll
        for (int g = 0; g < 4; ++g)
            #pragma unroll
            for (int reg = 0; reg < 4; ++reg)
                sP[wave][(row_g + reg) * KLDP + g * 16 + r] = (short)f2bf(s[g][reg]);
        asm volatile("s_waitcnt lgkmcnt(0)" ::: "memory");

        // O += P @ V   (A-frag from sP, B-frag from sV)
        #pragma unroll
        for (int dg = 0; dg < 4; ++dg) {
            #pragma unroll
            for (int kh = 0; kh < 2; ++kh) {
                bf16x8 pa = *reinterpret_cast<const bf16x8*>(&sP[wave][r * KLDP + kh * 32 + ko]);
                bf16x8 vb = *reinterpret_cast<const bf16x8*>(&sV[(dg * 16 + r) * KLDP + kh * 32 + ko]);
                oacc[dg] = __builtin_amdgcn_mfma_f32_16x16x32_bf16(pa, vb, oacc[dg], 0, 0, 0);
            }
        }
    }

    // normalize and write AV (bf16)
    float il[4];
    #pragma unroll
    for (int reg = 0; reg < 4; ++reg) il[reg] = 1.0f / lr[reg];
    #pragma unroll
    for (int dg = 0; dg < 4; ++dg) {
        #pragma unroll
        for (int reg = 0; reg < 4; ++reg) {
            float v = oacc[dg][reg] * il[reg];
            size_t tok = (size_t)(b * SEQ + q_base + row_g + reg);
            av[tok * HID + h * DHEAD + dg * 16 + r] = (short)f2bf(v);
        }
    }
}

extern "C" void kernel_launch(void* const* d_in, const int* in_sizes, int n_in,
                              void* d_out, int out_size, void* d_ws, size_t ws_size,
                              hipStream_t stream) {
    const float* x     = (const float*)d_in[0];
    const float* W_qkv = (const float*)d_in[1];
    const float* b_qkv = (const float*)d_in[2];
    const float* W_o   = (const float*)d_in[3];
    const float* b_o   = (const float*)d_in[4];
    float* out = (float*)d_out;

    const int n_x    = NTOK * HID;        // 4,194,304
    const int n_wqkv = QKV_N * HID;       // 3,145,728
    const int n_wo   = HID * HID;         // 1,048,576
    const int n_qkv  = NTOK * QKV_N;      // 12,582,912
    const int n_av   = NTOK * HID;        // 4,194,304

    short* xb    = (short*)d_ws;
    short* wqkvb = xb + n_x;
    short* wob   = wqkvb + n_wqkv;
    short* qkv   = wob + n_wo;
    short* av    = qkv + n_qkv;

    cast_f32_bf16<<<n_x / 1024,    256, 0, stream>>>(x,     (unsigned short*)xb,    n_x / 4);
    cast_f32_bf16<<<n_wqkv / 1024, 256, 0, stream>>>(W_qkv, (unsigned short*)wqkvb, n_wqkv / 4);
    cast_f32_bf16<<<n_wo / 1024,   256, 0, stream>>>(W_o,   (unsigned short*)wob,   n_wo / 4);

    // qkv = x @ W_qkv^T + b_qkv  -> bf16 [4096][3072]
    gemm_bt<true><<<dim3(QKV_N / 128, NTOK / 128), 256, 0, stream>>>(
        xb, wqkvb, b_qkv, (void*)qkv, NTOK, QKV_N, HID);

    // attention -> av bf16 [4096][1024]
    attn_fwd<<<dim3(SEQ / 64, BATCH * NHEAD), 256, 0, stream>>>(qkv, av);

    // out = av @ W_o^T + b_o  -> fp32
    gemm_bt<false><<<dim3(HID / 128, NTOK / 128), 256, 0, stream>>>(
        av, wob, b_o, (void*)out, NTOK, HID, HID);
}

// Round 2
// 194.972 us; speedup vs baseline: 1.2584x; 1.2584x over previous
//
#include <hip/hip_runtime.h>
#include <cstdint>
#include <cstddef>

// ---------- constants for this problem ----------
#define BATCH 2
#define SEQ   2048
#define HID   1024
#define NHEAD 16
#define DHEAD 64
#define QKV_N 3072   // 3*HID
#define NTOK  4096   // BATCH*SEQ

typedef __attribute__((ext_vector_type(4))) float f32x4;
typedef __attribute__((ext_vector_type(8))) short bf16x8;

__device__ inline unsigned short f2bf(float f) {
    union { float f; unsigned int u; } v; v.f = f;
    unsigned int u = v.u;
    unsigned int r = (u + 0x7fffu + ((u >> 16) & 1u)) >> 16;
    return (unsigned short)r;
}

// ---------- cast fp32 -> bf16 (packed ushort4) ----------
__global__ void cast_f32_bf16(const float* __restrict__ in, unsigned short* __restrict__ out, int n4) {
    int i = blockIdx.x * blockDim.x + threadIdx.x;
    if (i >= n4) return;
    float4 v = reinterpret_cast<const float4*>(in)[i];
    ushort4 o;
    o.x = f2bf(v.x); o.y = f2bf(v.y); o.z = f2bf(v.z); o.w = f2bf(v.w);
    reinterpret_cast<ushort4*>(out)[i] = o;
}

// ---------- GEMM: C[M][N] = A[M][K](bf16) @ B[N][K](bf16)^T + bias (fp32) ----------
// tile 128x128, BK=32, 4 waves (2x2), each wave 64x64 via 4x4 frags of 16x16x32
// OUT_MODE: 0 = fp32 row-major, 1 = bf16 row-major, 2 = qkv-mode (bf16 row-major
//           for n<2*HID, transposed V^T [bh][d][s] for n>=2*HID)
#define LDP 40   // LDS row pitch in bf16 elements (32 + 8 pad)

template<int OUT_MODE>
__global__ __launch_bounds__(256) void gemm_bt(const short* __restrict__ A,
                                               const short* __restrict__ B,
                                               const float* __restrict__ bias,
                                               void* __restrict__ Cout,
                                               short* __restrict__ vT,
                                               int M, int N, int K) {
    __shared__ short sA[128 * LDP];
    __shared__ short sB[128 * LDP];
    const int tid  = threadIdx.x;
    const int lane = tid & 63;
    const int wave = tid >> 6;
    const int wm = wave >> 1, wn = wave & 1;
    const int m0 = blockIdx.y * 128;
    const int n0 = blockIdx.x * 128;

    f32x4 acc[4][4];
    #pragma unroll
    for (int i = 0; i < 4; ++i)
        #pragma unroll
        for (int j = 0; j < 4; ++j) acc[i][j] = (f32x4){0.f, 0.f, 0.f, 0.f};

    const int srow = tid >> 1;          // 0..127
    const int soff = (tid & 1) * 2;     // int4-chunk offset {0,2} within row
    const int r  = lane & 15;
    const int ko = (lane >> 4) * 8;

    for (int kt = 0; kt < K; kt += 32) {
        __syncthreads();
        {
            const int4* ga = reinterpret_cast<const int4*>(A + (size_t)(m0 + srow) * K + kt + soff * 8);
            int4 a0 = ga[0]; int4 a1 = ga[1];
            const int4* gb = reinterpret_cast<const int4*>(B + (size_t)(n0 + srow) * K + kt + soff * 8);
            int4 b0 = gb[0]; int4 b1 = gb[1];
            *reinterpret_cast<int4*>(&sA[srow * LDP + soff * 8])     = a0;
            *reinterpret_cast<int4*>(&sA[srow * LDP + soff * 8 + 8]) = a1;
            *reinterpret_cast<int4*>(&sB[srow * LDP + soff * 8])     = b0;
            *reinterpret_cast<int4*>(&sB[srow * LDP + soff * 8 + 8]) = b1;
        }
        __syncthreads();

        bf16x8 af[4], bfr[4];
        #pragma unroll
        for (int i = 0; i < 4; ++i) {
            af[i]  = *reinterpret_cast<const bf16x8*>(&sA[(wm * 64 + i * 16 + r) * LDP + ko]);
            bfr[i] = *reinterpret_cast<const bf16x8*>(&sB[(wn * 64 + i * 16 + r) * LDP + ko]);
        }
        #pragma unroll
        for (int i = 0; i < 4; ++i)
            #pragma unroll
            for (int j = 0; j < 4; ++j)
                acc[i][j] = __builtin_amdgcn_mfma_f32_16x16x32_bf16(af[i], bfr[j], acc[i][j], 0, 0, 0);
    }

    // epilogue: D layout col=lane&15, row=4*(lane>>4)+reg
    const int col_l = lane & 15;
    const int row_g = (lane >> 4) * 4;

    if (OUT_MODE == 2 && n0 >= 2 * HID) {
        // V^T path: write vT[((b*NHEAD+h)*DHEAD + d)][s], s = token within batch
        #pragma unroll
        for (int i = 0; i < 4; ++i) {
            #pragma unroll
            for (int j = 0; j < 4; ++j) {
                int nn  = n0 + wn * 64 + j * 16 + col_l;
                int idx = nn - 2 * HID;
                int hh  = idx >> 6, dd = idx & 63;
                float bv = bias[nn];
                int mm0 = m0 + wm * 64 + i * 16 + row_g;   // 4 consecutive tokens
                int bb  = mm0 >> 11, ss = mm0 & 2047;
                ushort4 pk;
                pk.x = f2bf(acc[i][j][0] + bv);
                pk.y = f2bf(acc[i][j][1] + bv);
                pk.z = f2bf(acc[i][j][2] + bv);
                pk.w = f2bf(acc[i][j][3] + bv);
                *reinterpret_cast<ushort4*>(
                    &vT[((size_t)(bb * NHEAD + hh) * DHEAD + dd) * SEQ + ss]) = pk;
            }
        }
        return;
    }

    #pragma unroll
    for (int i = 0; i < 4; ++i) {
        #pragma unroll
        for (int j = 0; j < 4; ++j) {
            int nn = n0 + wn * 64 + j * 16 + col_l;
            float bv = bias[nn];
            #pragma unroll
            for (int reg = 0; reg < 4; ++reg) {
                int mm = m0 + wm * 64 + i * 16 + row_g + reg;
                float v = acc[i][j][reg] + bv;
                if (OUT_MODE == 0) {
                    reinterpret_cast<float*>(Cout)[(size_t)mm * N + nn] = v;
                } else {
                    reinterpret_cast<unsigned short*>(Cout)[(size_t)mm * N + nn] = f2bf(v);
                }
            }
        }
    }
}

// ---------- flash attention (causal), bf16 MFMA ----------
// grid (32, 32): x = j, y = bh; qt = (j + y) & 31 (hash so co-resident blocks
// get complementary work). Block = 128 threads = 2 waves, each wave 32 q-rows.
#define KLDP 72  // LDS pitch (64 + 8 pad), rows 16B-aligned (144 B)

__global__ __launch_bounds__(128, 2) void attn_fwd(const short* __restrict__ qkv,
                                                   const short* __restrict__ vT,
                                                   short* __restrict__ av) {
    const int bh = blockIdx.y;
    const int b  = bh >> 4;        // NHEAD = 16
    const int h  = bh & 15;
    const int qt = (blockIdx.x + blockIdx.y) & 31;

    __shared__ short sK [64 * KLDP];       // K tile  [kv][d]
    __shared__ short sVT[64 * KLDP];       // V^T tile [d][kv]
    __shared__ short sP [2][32 * KLDP];    // per-wave P tile [row][kv]

    const int tid  = threadIdx.x;          // 0..127
    const int lane = tid & 63;
    const int wave = tid >> 6;             // 0..1
    const int r    = lane & 15;
    const int G    = lane >> 4;            // 0..3
    const int ko   = G * 8;
    const int row_g = G * 4;

    const int qbw = qt * 64 + wave * 32;   // wave's first q row

    // Q fragments in registers for the whole kv loop
    bf16x8 qf[2][2];
    #pragma unroll
    for (int mi = 0; mi < 2; ++mi) {
        const short* Qg = qkv + ((size_t)(b * SEQ + qbw + mi * 16 + r)) * QKV_N + h * DHEAD;
        qf[mi][0] = *reinterpret_cast<const bf16x8*>(Qg + ko);
        qf[mi][1] = *reinterpret_cast<const bf16x8*>(Qg + 32 + ko);
    }

    f32x4 oacc[2][4];
    f32x4 oL[2];
    float mr[2][4];
    #pragma unroll
    for (int mi = 0; mi < 2; ++mi) {
        oL[mi] = (f32x4){0.f, 0.f, 0.f, 0.f};
        #pragma unroll
        for (int dg = 0; dg < 4; ++dg) oacc[mi][dg] = (f32x4){0.f, 0.f, 0.f, 0.f};
        #pragma unroll
        for (int reg = 0; reg < 4; ++reg) mr[mi][reg] = -3.0e38f;
    }

    bf16x8 ones;
    #pragma unroll
    for (int e = 0; e < 8; ++e) ones[e] = (short)0x3f80;   // bf16 1.0

    const float SCL = 0.18033688011112042f;  // (1/8) * log2(e)

    for (int t = 0; t <= qt; ++t) {
        const int kv0 = t * 64;
        __syncthreads();
        // stage K tile and V^T tile: 512 int4 chunks each, 128 threads -> 4+4 per thread
        #pragma unroll
        for (int i = 0; i < 4; ++i) {
            int idx = i * 128 + tid;       // 0..511
            int row = idx >> 3, c = idx & 7;
            int4 kk = *reinterpret_cast<const int4*>(
                qkv + ((size_t)(b * SEQ + kv0 + row)) * QKV_N + HID + h * DHEAD + c * 8);
            *reinterpret_cast<int4*>(&sK[row * KLDP + c * 8]) = kk;
            int4 vv = *reinterpret_cast<const int4*>(
                vT + ((size_t)(bh * DHEAD + row)) * SEQ + kv0 + c * 8);
            *reinterpret_cast<int4*>(&sVT[row * KLDP + c * 8]) = vv;
        }
        __syncthreads();

        // K fragments (shared between both mi)
        bf16x8 kb[4][2];
        #pragma unroll
        for (int g = 0; g < 4; ++g) {
            kb[g][0] = *reinterpret_cast<const bf16x8*>(&sK[(g * 16 + r) * KLDP + ko]);
            kb[g][1] = *reinterpret_cast<const bf16x8*>(&sK[(g * 16 + r) * KLDP + 32 + ko]);
        }

        const bool diag = (t == qt);

        #pragma unroll
        for (int mi = 0; mi < 2; ++mi) {
            // S = Q @ K^T (log2-scaled)
            f32x4 s[4];
            #pragma unroll
            for (int g = 0; g < 4; ++g) {
                f32x4 z = (f32x4){0.f, 0.f, 0.f, 0.f};
                z = __builtin_amdgcn_mfma_f32_16x16x32_bf16(qf[mi][0], kb[g][0], z, 0, 0, 0);
                z = __builtin_amdgcn_mfma_f32_16x16x32_bf16(qf[mi][1], kb[g][1], z, 0, 0, 0);
                s[g] = z;
            }
            #pragma unroll
            for (int g = 0; g < 4; ++g) {
                #pragma unroll
                for (int reg = 0; reg < 4; ++reg) {
                    float sv = s[g][reg] * SCL;
                    if (diag) {
                        int kvg = kv0 + g * 16 + r;               // D col = lane&15
                        int qg  = qbw + mi * 16 + row_g + reg;    // D row
                        if (kvg > qg) sv = -1.0e30f;
                    }
                    s[g][reg] = sv;
                }
            }

            // row max over 64 kv (4 reg-groups x 16 lanes)
            float rm[4];
            #pragma unroll
            for (int reg = 0; reg < 4; ++reg)
                rm[reg] = fmaxf(fmaxf(s[0][reg], s[1][reg]), fmaxf(s[2][reg], s[3][reg]));
            #pragma unroll
            for (int m = 1; m <= 8; m <<= 1) {
                #pragma unroll
                for (int reg = 0; reg < 4; ++reg)
                    rm[reg] = fmaxf(rm[reg], __shfl_xor(rm[reg], m));
            }

            float mnew[4], corr[4];
            #pragma unroll
            for (int reg = 0; reg < 4; ++reg) {
                mnew[reg] = fmaxf(mr[mi][reg], rm[reg]);
                corr[reg] = __builtin_amdgcn_exp2f(mr[mi][reg] - mnew[reg]);
                mr[mi][reg] = mnew[reg];
            }
            #pragma unroll
            for (int dg = 0; dg < 4; ++dg)
                #pragma unroll
                for (int reg = 0; reg < 4; ++reg)
                    oacc[mi][dg][reg] *= corr[reg];
            #pragma unroll
            for (int reg = 0; reg < 4; ++reg) oL[mi][reg] *= corr[reg];

            // P = exp2(S - m) -> bf16 -> per-wave LDS [row][kv]
            #pragma unroll
            for (int g = 0; g < 4; ++g) {
                #pragma unroll
                for (int reg = 0; reg < 4; ++reg) {
                    float p = __builtin_amdgcn_exp2f(s[g][reg] - mnew[reg]);
                    sP[wave][(mi * 16 + row_g + reg) * KLDP + g * 16 + r] = (short)f2bf(p);
                }
            }
        }

        asm volatile("s_waitcnt lgkmcnt(0)" ::: "memory");
        __builtin_amdgcn_sched_barrier(0);

        // V fragments (shared between both mi)
        bf16x8 vb[4][2];
        #pragma unroll
        for (int dg = 0; dg < 4; ++dg) {
            vb[dg][0] = *reinterpret_cast<const bf16x8*>(&sVT[(dg * 16 + r) * KLDP + ko]);
            vb[dg][1] = *reinterpret_cast<const bf16x8*>(&sVT[(dg * 16 + r) * KLDP + 32 + ko]);
        }

        // O += P @ V ; l += P @ 1 (ones-trick row sums, broadcast in all lanes)
        #pragma unroll
        for (int mi = 0; mi < 2; ++mi) {
            bf16x8 pa0 = *reinterpret_cast<const bf16x8*>(&sP[wave][(mi * 16 + r) * KLDP + ko]);
            bf16x8 pa1 = *reinterpret_cast<const bf16x8*>(&sP[wave][(mi * 16 + r) * KLDP + 32 + ko]);
            #pragma unroll
            for (int dg = 0; dg < 4; ++dg) {
                oacc[mi][dg] = __builtin_amdgcn_mfma_f32_16x16x32_bf16(pa0, vb[dg][0], oacc[mi][dg], 0, 0, 0);
                oacc[mi][dg] = __builtin_amdgcn_mfma_f32_16x16x32_bf16(pa1, vb[dg][1], oacc[mi][dg], 0, 0, 0);
            }
            oL[mi] = __builtin_amdgcn_mfma_f32_16x16x32_bf16(pa0, ones, oL[mi], 0, 0, 0);
            oL[mi] = __builtin_amdgcn_mfma_f32_16x16x32_bf16(pa1, ones, oL[mi], 0, 0, 0);
        }
    }

    // normalize and write AV (bf16)
    #pragma unroll
    for (int mi = 0; mi < 2; ++mi) {
        float il[4];
        #pragma unroll
        for (int reg = 0; reg < 4; ++reg) il[reg] = 1.0f / oL[mi][reg];
        #pragma unroll
        for (int dg = 0; dg < 4; ++dg) {
            #pragma unroll
            for (int reg = 0; reg < 4; ++reg) {
                float v = oacc[mi][dg][reg] * il[reg];
                size_t tok = (size_t)(b * SEQ + qbw + mi * 16 + row_g + reg);
                av[tok * HID + h * DHEAD + dg * 16 + r] = (short)f2bf(v);
            }
        }
    }
}

extern "C" void kernel_launch(void* const* d_in, const int* in_sizes, int n_in,
                              void* d_out, int out_size, void* d_ws, size_t ws_size,
                              hipStream_t stream) {
    const float* x     = (const float*)d_in[0];
    const float* W_qkv = (const float*)d_in[1];
    const float* b_qkv = (const float*)d_in[2];
    const float* W_o   = (const float*)d_in[3];
    const float* b_o   = (const float*)d_in[4];
    float* out = (float*)d_out;

    const int n_x    = NTOK * HID;        // 4,194,304
    const int n_wqkv = QKV_N * HID;       // 3,145,728
    const int n_wo   = HID * HID;         // 1,048,576
    const int n_qkv  = NTOK * QKV_N;      // 12,582,912
    const int n_av   = NTOK * HID;        // 4,194,304
    const int n_vT   = NTOK * HID;        // 4,194,304 (V^T [b][h][d][s])

    short* xb    = (short*)d_ws;
    short* wqkvb = xb + n_x;
    short* wob   = wqkvb + n_wqkv;
    short* qkv   = wob + n_wo;
    short* av    = qkv + n_qkv;
    short* vT    = av + n_av;

    cast_f32_bf16<<<n_x / 1024,    256, 0, stream>>>(x,     (unsigned short*)xb,    n_x / 4);
    cast_f32_bf16<<<n_wqkv / 1024, 256, 0, stream>>>(W_qkv, (unsigned short*)wqkvb, n_wqkv / 4);
    cast_f32_bf16<<<n_wo / 1024,   256, 0, stream>>>(W_o,   (unsigned short*)wob,   n_wo / 4);

    // qkv = x @ W_qkv^T + b_qkv  -> bf16 [4096][3072] (Q,K) + V^T [32][64][2048]
    gemm_bt<2><<<dim3(QKV_N / 128, NTOK / 128), 256, 0, stream>>>(
        xb, wqkvb, b_qkv, (void*)qkv, vT, NTOK, QKV_N, HID);

    // attention -> av bf16 [4096][1024]
    attn_fwd<<<dim3(32, 32), 128, 0, stream>>>(qkv, vT, av);

    // out = av @ W_o^T + b_o  -> fp32
    gemm_bt<0><<<dim3(HID / 128, NTOK / 128), 256, 0, stream>>>(
        av, wob, b_o, (void*)out, nullptr, NTOK, HID, HID);
}